// Round 11
// baseline (195.012 us; speedup 1.0000x reference)
//
#include <hip/hip_runtime.h>
#include <hip/hip_bf16.h>
#include <cstdint>
#include <cstddef>

// Problem constants (B, S, E, H, MAXLEN) = (2, 2048, 1024, 16, 2048)
constexpr int Sn = 2048;
constexpr int En = 1024;
constexpr int Bn = 2;
constexpr int Hn = 16;
constexpr int CHUNK = 64;
constexpr int NCH = Sn / CHUNK;    // 32 chunks per batch
constexpr int Mtot = Bn * Sn;      // 4096
constexpr int GCH = Mtot / CHUNK;  // 64 global chunks

typedef __bf16 bf16x8 __attribute__((ext_vector_type(8)));
typedef float  f32x4  __attribute__((ext_vector_type(4)));

__device__ __forceinline__ unsigned short f2bf(float f) {
    union { float f; uint32_t u; } v; v.f = f;
    const uint32_t u = v.u;
    return (unsigned short)((u + 0x7fffu + ((u >> 16) & 1u)) >> 16);  // RNE
}
__device__ __forceinline__ float bf2f(unsigned short s) {
    union { uint32_t u; float f; } v; v.u = (uint32_t)s << 16; return v.f;
}
// Pack two fp32 -> two bf16 (RNE) in one dword (v_cvt_pk_bf16_f32).
__device__ __forceinline__ uint32_t pkbf(float a, float b) {
    union { __hip_bfloat162 h; uint32_t u; } v;
    v.h = __float22bfloat162_rn(float2{a, b});
    return v.u;
}
#define PK16(r0, r1) uint4{ pkbf((r0).x,(r0).y), pkbf((r0).z,(r0).w), \
                            pkbf((r1).x,(r1).y), pkbf((r1).z,(r1).w) }

// ---------------------------------------------------------------------------
// bf16 MFMA GEMM (NT) with fused fp32->bf16 staging cast (R11).
// C[m,n] = sum_k A[m,k]*W[n,k] + bias[n];  W is ALWAYS fp32 (Wv / Wo, cast
// during staging);  A is fp32 (x) when CAST_A, else bf16 (opre).
// Tile 128(M) x 64(N), BK=64, 256 threads = 4 waves in 2x2, wave tile 64x32.
// Staging: global -> named VGPRs -> (packed cvt) -> ds_write_b128; loads for
// iter i+1 issue before iter i's compute (private VGPRs are not drained at
// __syncthreads). LDS: 1024 B chunk = 16 rows x 32 k in fragment order,
// lane l -> slot l*16 B (conflict-free b128).
// XCD swizzle: id -> xcd = id&7 owns 4 contiguous row-blocks; A slice + B
// fit the per-XCD 4 MB L2.
// FUSE_CSUM: wave wr's 64 rows = global chunk 2*by+wr; butterfly shuffle
// gives exact per-chunk column sums (unique writer).
// ---------------------------------------------------------------------------
#define LOAD_SET(S, k0)                                                        \
    if constexpr (CAST_A) {                                                    \
        S##a00 = *(const float4*)(gAf0 + (k0));                                \
        S##a01 = *(const float4*)(gAf0 + (k0) + 4);                            \
        S##a10 = *(const float4*)(gAf0 + (k0) + 32);                           \
        S##a11 = *(const float4*)(gAf0 + (k0) + 36);                           \
        S##a20 = *(const float4*)(gAf1 + (k0));                                \
        S##a21 = *(const float4*)(gAf1 + (k0) + 4);                            \
        S##a30 = *(const float4*)(gAf1 + (k0) + 32);                           \
        S##a31 = *(const float4*)(gAf1 + (k0) + 36);                           \
    } else {                                                                   \
        S##h0 = *(const uint4*)(gAh0 + (k0));                                  \
        S##h1 = *(const uint4*)(gAh0 + (k0) + 32);                             \
        S##h2 = *(const uint4*)(gAh1 + (k0));                                  \
        S##h3 = *(const uint4*)(gAh1 + (k0) + 32);                             \
    }                                                                          \
    S##b00 = *(const float4*)(gBf + (k0));                                     \
    S##b01 = *(const float4*)(gBf + (k0) + 4);                                 \
    S##b10 = *(const float4*)(gBf + (k0) + 32);                                \
    S##b11 = *(const float4*)(gBf + (k0) + 36);

#define STORE_SET(S)                                                           \
    if constexpr (CAST_A) {                                                    \
        *lA00 = PK16(S##a00, S##a01);                                          \
        *lA01 = PK16(S##a10, S##a11);                                          \
        *lA10 = PK16(S##a20, S##a21);                                          \
        *lA11 = PK16(S##a30, S##a31);                                          \
    } else {                                                                   \
        *lA00 = S##h0; *lA01 = S##h1; *lA10 = S##h2; *lA11 = S##h3;            \
    }                                                                          \
    *lB00 = PK16(S##b00, S##b01);                                              \
    *lB01 = PK16(S##b10, S##b11);

#define COMPUTE()                                                                              \
    {                                                                                          \
        bf16x8 af[4][2], bfr[2][2];                                                            \
        _Pragma("unroll")                                                                      \
        for (int i = 0; i < 4; ++i)                                                            \
            _Pragma("unroll")                                                                  \
            for (int kh = 0; kh < 2; ++kh)                                                     \
                af[i][kh] = *(const bf16x8*)&As[((wr * 4 + i) * 2 + kh) * 512 + lane * 8];      \
        _Pragma("unroll")                                                                      \
        for (int j = 0; j < 2; ++j)                                                            \
            _Pragma("unroll")                                                                  \
            for (int kh = 0; kh < 2; ++kh)                                                     \
                bfr[j][kh] = *(const bf16x8*)&Bs[((wc * 2 + j) * 2 + kh) * 512 + lane * 8];     \
        _Pragma("unroll")                                                                      \
        for (int kh = 0; kh < 2; ++kh)                                                         \
            _Pragma("unroll")                                                                  \
            for (int i = 0; i < 4; ++i)                                                        \
                _Pragma("unroll")                                                              \
                for (int j = 0; j < 2; ++j)                                                    \
                    acc[i][j] = __builtin_amdgcn_mfma_f32_16x16x32_bf16(af[i][kh], bfr[j][kh], \
                                                                        acc[i][j], 0, 0, 0);   \
    }

template<bool CAST_A, bool APPLY_MASK, bool OUT_BF16, bool FUSE_CSUM>
__global__ __launch_bounds__(256)
void gemm_fused(const void* __restrict__ Av, const float* __restrict__ Wf,
                const float* __restrict__ bias, const int* __restrict__ mask,
                void* __restrict__ Cv, float* __restrict__ csum)
{
    __shared__ __align__(16) unsigned short As[128 * 64];  // 16 KB
    __shared__ __align__(16) unsigned short Bs[64 * 64];   // 8 KB

    const int tid  = threadIdx.x;
    const int lane = tid & 63;
    const int wv   = tid >> 6;      // wave 0..3
    const int wr   = wv >> 1;       // wave row (0..1) -> M
    const int wc   = wv & 1;        // wave col (0..1) -> N
    // XCD-aware swizzle (grid (16, 32)).
    const int id   = blockIdx.y * 16 + blockIdx.x;
    const int xcd  = id & 7;
    const int slot = id >> 3;
    const int by   = xcd * 4 + (slot >> 4);
    const int bx   = slot & 15;
    const int bm   = by * 128;
    const int bn   = bx * 64;
    const int m16  = lane & 15;
    const int kq   = lane >> 4;     // k-quarter (staging) / row-quad (C/D)

    f32x4 acc[4][2] = {};

    const int rg0 = 2 * wv, rg1 = 2 * wv + 1;
    const float*          gAf0 = nullptr; const float*          gAf1 = nullptr;
    const unsigned short* gAh0 = nullptr; const unsigned short* gAh1 = nullptr;
    if constexpr (CAST_A) {
        gAf0 = (const float*)Av + (size_t)(bm + 16 * rg0 + m16) * En + kq * 8;
        gAf1 = (const float*)Av + (size_t)(bm + 16 * rg1 + m16) * En + kq * 8;
    } else {
        gAh0 = (const unsigned short*)Av + (size_t)(bm + 16 * rg0 + m16) * En + kq * 8;
        gAh1 = (const unsigned short*)Av + (size_t)(bm + 16 * rg1 + m16) * En + kq * 8;
    }
    const float* gBf = Wf + (size_t)(bn + 16 * wv + m16) * En + kq * 8;

    uint4* lA00 = (uint4*)&As[(rg0 * 2 + 0) * 512 + lane * 8];
    uint4* lA01 = (uint4*)&As[(rg0 * 2 + 1) * 512 + lane * 8];
    uint4* lA10 = (uint4*)&As[(rg1 * 2 + 0) * 512 + lane * 8];
    uint4* lA11 = (uint4*)&As[(rg1 * 2 + 1) * 512 + lane * 8];
    uint4* lB00 = (uint4*)&Bs[(wv  * 2 + 0) * 512 + lane * 8];
    uint4* lB01 = (uint4*)&Bs[(wv  * 2 + 1) * 512 + lane * 8];

    // Two sets of individually named staging registers (arrays spill — R6).
    float4 pa00, pa01, pa10, pa11, pa20, pa21, pa30, pa31;
    uint4  ph0, ph1, ph2, ph3;
    float4 pb00, pb01, pb10, pb11;
    float4 qa00, qa01, qa10, qa11, qa20, qa21, qa30, qa31;
    uint4  qh0, qh1, qh2, qh3;
    float4 qb00, qb01, qb10, qb11;

    LOAD_SET(p, 0);
    // K=1024, BK=64 -> 16 steps, 2x unrolled (alternating reg sets).
#pragma unroll 1
    for (int it = 0; it < 8; ++it) {
        const int kbase = it * 128;
        __syncthreads();                 // prev compute's LDS reads done
        STORE_SET(p);                    // vmcnt waits for p (1 iter old)
        __syncthreads();                 // writes visible
        LOAD_SET(q, kbase + 64);         // in flight across the MFMAs
        COMPUTE();

        __syncthreads();
        STORE_SET(q);
        __syncthreads();
        if (it < 7) { LOAD_SET(p, kbase + 128); }
        COMPUTE();
    }

    // Epilogue. C/D layout: col = lane&15, row = (lane>>4)*4 + reg.
    float colsum[2] = {0.0f, 0.0f};
#pragma unroll
    for (int i = 0; i < 4; ++i) {
        const int r0 = bm + wr * 64 + i * 16 + kq * 4;
#pragma unroll
        for (int j = 0; j < 2; ++j) {
            const int c0 = bn + wc * 32 + j * 16 + m16;
            const float bcol = bias[c0];
#pragma unroll
            for (int r = 0; r < 4; ++r) {
                const int row = r0 + r;
                float val = acc[i][j][r] + bcol;
                if (APPLY_MASK) val = (mask[row] == 0) ? 0.0f : val;
                if (FUSE_CSUM) colsum[j] += val;
                if (OUT_BF16)
                    ((unsigned short*)Cv)[(size_t)row * En + c0] = f2bf(val);
                else
                    ((float*)Cv)[(size_t)row * En + c0] = val;
            }
        }
    }

    if (FUSE_CSUM) {
        // Wave wr's 64 rows are exactly global chunk gc = 2*by + wr.
        const int gc = 2 * by + wr;
#pragma unroll
        for (int j = 0; j < 2; ++j) {
            float s = colsum[j];
            s += __shfl_xor(s, 16, 64);
            s += __shfl_xor(s, 32, 64);
            if (kq == 0)
                csum[(size_t)gc * En + bn + wc * 32 + j * 16 + m16] = s;
        }
    }
}

// ---------------------------------------------------------------------------
// combine: inline exclusive scan of csum (32 chunk sums per column) +
// within-chunk prefix + weighted combine -> opre (bf16).
// out_pre[b,i,e] = (w2*Pref[i&~1] + (i odd)*w1*vm[i-1] + w0*(T - Pref[i])) / Z
// Z = (i&~1)*w2 + (i odd)*w1 + (S-i)*w0 + 1e-8   (pre-mask normalization)
// ---------------------------------------------------------------------------
__global__ __launch_bounds__(256)
void combine(const unsigned short* __restrict__ vm, const float* __restrict__ csum,
             const float* __restrict__ hier, unsigned short* __restrict__ opre)
{
    const int e = blockIdx.x * 256 + threadIdx.x;
    const int c = blockIdx.y;     // chunk within batch, 0..31
    const int b = blockIdx.z;
    const int h = e >> 6;   // dh = 64

    const float w0 = hier[((size_t)b * Hn + h) * 3 + 0];
    const float w1 = hier[((size_t)b * Hn + h) * 3 + 1] * 0.5f;
    const float w2 = hier[((size_t)b * Hn + h) * 3 + 2] * 0.25f;

    // Inline exclusive scan over this batch's 32 chunk sums (L2-hot).
    float run = 0.0f, T = 0.0f;
    const int g0 = b * NCH;
    for (int c2 = 0; c2 < NCH; ++c2) {
        const float v = csum[(size_t)(g0 + c2) * En + e];
        if (c2 < c) run += v;
        T += v;
    }

    float prev = 0.0f;
    const size_t base = ((size_t)b * Sn + c * CHUNK) * En + e;

    for (int t = 0; t < CHUNK; ++t) {
        const int i = c * CHUNK + t;
        const float cur = bf2f(vm[base + (size_t)t * En]);
        float num, Z;
        if (i & 1) {
            num = w2 * (run - prev) + w1 * prev + w0 * (T - run);
            Z = (float)(i - 1) * w2 + w1 + (float)(Sn - i) * w0 + 1e-8f;
        } else {
            num = w2 * run + w0 * (T - run);
            Z = (float)i * w2 + (float)(Sn - i) * w0 + 1e-8f;
        }
        opre[base + (size_t)t * En] = f2bf(num / Z);
        run += cur;
        prev = cur;
    }
}

// ---------------------------------------------------------------------------
extern "C" void kernel_launch(void* const* d_in, const int* in_sizes, int n_in,
                              void* d_out, int out_size, void* d_ws, size_t ws_size,
                              hipStream_t stream)
{
    // 0:x 1:attention_mask 2:level_indices 3:Wq 4:bq 5:Wk 6:bk 7:Wv 8:bv 9:hier 10:Wo 11:bo
    const float* x    = (const float*)d_in[0];
    const int*   mask = (const int*)d_in[1];
    const float* Wv   = (const float*)d_in[7];
    const float* bv   = (const float*)d_in[8];
    const float* hier = (const float*)d_in[9];
    const float* Wo   = (const float*)d_in[10];
    const float* bo   = (const float*)d_in[11];
    float* out = (float*)d_out;

    char* ws = (char*)d_ws;
    unsigned short* vmb   = (unsigned short*)ws;  ws += (size_t)Mtot * En * 2;   // 8 MB
    float*          csum  = (float*)ws;           ws += (size_t)GCH * En * 4;    // 256 KB
    unsigned short* opreb = (unsigned short*)ws;  ws += (size_t)Mtot * En * 2;   // 8 MB

    dim3 threads(256);
    dim3 gemm_grid(16, 32);   // 512 blocks = 2/CU (XCD-swizzled in-kernel)

    // 1) vm = mask ? (x @ Wv.T + bv) : 0 (bf16) + fused per-chunk column sums.
    //    x and Wv are fp32; cast happens inside the staging path.
    gemm_fused<true, true, true, true><<<gemm_grid, threads, 0, stream>>>(
        x, Wv, bv, mask, vmb, csum);
    // 2) weighted combine (inline csum scan) -> opre (bf16)
    combine<<<dim3(En / 256, NCH, Bn), threads, 0, stream>>>(vmb, csum, hier, opreb);
    // 3) out = opre @ Wo.T + bo (fp32 out); opre bf16, Wo fp32 cast in staging.
    gemm_fused<false, false, false, false><<<gemm_grid, threads, 0, stream>>>(
        opreb, Wo, bo, nullptr, out, nullptr);
}

// Round 12
// 171.410 us; speedup vs baseline: 1.1377x; 1.1377x over previous
//
#include <hip/hip_runtime.h>
#include <cstdint>
#include <cstddef>

// Problem constants (B, S, E, H, MAXLEN) = (2, 2048, 1024, 16, 2048)
constexpr int Sn = 2048;
constexpr int En = 1024;
constexpr int Bn = 2;
constexpr int Hn = 16;
constexpr int CHUNK = 64;
constexpr int NCH = Sn / CHUNK;    // 32 chunks per batch
constexpr int Mtot = Bn * Sn;      // 4096
constexpr int GCH = Mtot / CHUNK;  // 64 global chunks

typedef __bf16 bf16x8 __attribute__((ext_vector_type(8)));
typedef float  f32x4  __attribute__((ext_vector_type(4)));

__device__ __forceinline__ unsigned short f2bf(float f) {
    union { float f; uint32_t u; } v; v.f = f;
    const uint32_t u = v.u;
    return (unsigned short)((u + 0x7fffu + ((u >> 16) & 1u)) >> 16);  // RNE
}
__device__ __forceinline__ float bf2f(unsigned short s) {
    union { uint32_t u; float f; } v; v.u = (uint32_t)s << 16; return v.f;
}

// ---------------------------------------------------------------------------
// Fused fp32 -> bf16 cast of x (XN), Wv (WN), Wo (WN) in one launch.
// ---------------------------------------------------------------------------
constexpr int XN = Bn * Sn * En;   // 4194304
constexpr int WN = En * En;        // 1048576

__global__ __launch_bounds__(256)
void cast3(const float* __restrict__ x, const float* __restrict__ Wv,
           const float* __restrict__ Wo, unsigned short* __restrict__ xb,
           unsigned short* __restrict__ Wvb, unsigned short* __restrict__ Wob)
{
    const int i = (blockIdx.x * 256 + threadIdx.x) * 4;
    const float* src; unsigned short* dst; int off;
    if (i < XN)           { src = x;  dst = xb;  off = i; }
    else if (i < XN + WN) { src = Wv; dst = Wvb; off = i - XN; }
    else                  { src = Wo; dst = Wob; off = i - XN - WN; }
    const float4 v = *(const float4*)(src + off);
    ushort4 o;
    o.x = f2bf(v.x); o.y = f2bf(v.y); o.z = f2bf(v.z); o.w = f2bf(v.w);
    *(ushort4*)(dst + off) = o;
}

// ---------------------------------------------------------------------------
// bf16 MFMA GEMM (NT) — R12: BK=128 register-prefetch for 2x memory-level
// parallelism. C[m,n] = sum_k A[m,k]*W[n,k] + bias[n].
// Tile 128(M) x 64(N), BK=128, 256 threads = 4 waves in 2x2, wave 64x32.
// R11's counters (MfmaUtil 5%, VALUBusy 12%, HBM 7%, 8.5k cyc/iter) showed
// the GEMM is MLP-limited: ~6 outstanding 16B loads/wave supports only
// ~1.4 TB/s at L2 latency. BK=128 keeps 12 loads (192 B) in flight per wave
// and halves barrier pairs (8 K-iters). LDS 48 KB -> 2 blocks/CU.
// Staging: global -> 24 named uint4 VGPRs (arrays spill: R6) -> ds_write_b128
// one full BK-128 phase after issue. LDS: 1024 B chunk = 16 rows x 32 k,
// fragment order, lane l -> slot l*16 B (conflict-free b128).
// XCD swizzle: xcd = id&7 owns 4 contiguous row-blocks; A 1 MB + B 2 MB < L2.
// FUSE_CSUM: wave wr's 64 rows = global chunk 2*by+wr (butterfly shuffle).
// ---------------------------------------------------------------------------
#define LOAD12(S, k0)                                \
    S##a0 = *(const uint4*)(gA0 + (k0));             \
    S##a1 = *(const uint4*)(gA0 + (k0) + 32);        \
    S##a2 = *(const uint4*)(gA0 + (k0) + 64);        \
    S##a3 = *(const uint4*)(gA0 + (k0) + 96);        \
    S##a4 = *(const uint4*)(gA1 + (k0));             \
    S##a5 = *(const uint4*)(gA1 + (k0) + 32);        \
    S##a6 = *(const uint4*)(gA1 + (k0) + 64);        \
    S##a7 = *(const uint4*)(gA1 + (k0) + 96);        \
    S##b0 = *(const uint4*)(gB0 + (k0));             \
    S##b1 = *(const uint4*)(gB0 + (k0) + 32);        \
    S##b2 = *(const uint4*)(gB0 + (k0) + 64);        \
    S##b3 = *(const uint4*)(gB0 + (k0) + 96);

#define STORE12(S)                                   \
    *lA0 = S##a0; *lA1 = S##a1; *lA2 = S##a2; *lA3 = S##a3; \
    *lA4 = S##a4; *lA5 = S##a5; *lA6 = S##a6; *lA7 = S##a7; \
    *lB0 = S##b0; *lB1 = S##b1; *lB2 = S##b2; *lB3 = S##b3;

#define COMPUTE128()                                                                           \
    {                                                                                          \
        _Pragma("unroll")                                                                      \
        for (int kh = 0; kh < 4; ++kh) {                                                       \
            bf16x8 af0 = *(const bf16x8*)&As[((wr * 4 + 0) * 4 + kh) * 512 + lane * 8];        \
            bf16x8 af1 = *(const bf16x8*)&As[((wr * 4 + 1) * 4 + kh) * 512 + lane * 8];        \
            bf16x8 af2 = *(const bf16x8*)&As[((wr * 4 + 2) * 4 + kh) * 512 + lane * 8];        \
            bf16x8 af3 = *(const bf16x8*)&As[((wr * 4 + 3) * 4 + kh) * 512 + lane * 8];        \
            bf16x8 bf0 = *(const bf16x8*)&Bs[((wc * 2 + 0) * 4 + kh) * 512 + lane * 8];        \
            bf16x8 bf1 = *(const bf16x8*)&Bs[((wc * 2 + 1) * 4 + kh) * 512 + lane * 8];        \
            acc[0][0] = __builtin_amdgcn_mfma_f32_16x16x32_bf16(af0, bf0, acc[0][0], 0, 0, 0); \
            acc[0][1] = __builtin_amdgcn_mfma_f32_16x16x32_bf16(af0, bf1, acc[0][1], 0, 0, 0); \
            acc[1][0] = __builtin_amdgcn_mfma_f32_16x16x32_bf16(af1, bf0, acc[1][0], 0, 0, 0); \
            acc[1][1] = __builtin_amdgcn_mfma_f32_16x16x32_bf16(af1, bf1, acc[1][1], 0, 0, 0); \
            acc[2][0] = __builtin_amdgcn_mfma_f32_16x16x32_bf16(af2, bf0, acc[2][0], 0, 0, 0); \
            acc[2][1] = __builtin_amdgcn_mfma_f32_16x16x32_bf16(af2, bf1, acc[2][1], 0, 0, 0); \
            acc[3][0] = __builtin_amdgcn_mfma_f32_16x16x32_bf16(af3, bf0, acc[3][0], 0, 0, 0); \
            acc[3][1] = __builtin_amdgcn_mfma_f32_16x16x32_bf16(af3, bf1, acc[3][1], 0, 0, 0); \
        }                                                                                      \
    }

template<bool APPLY_MASK, bool OUT_BF16, bool FUSE_CSUM>
__global__ __launch_bounds__(256)
void gemm_bk128(const unsigned short* __restrict__ A, const unsigned short* __restrict__ Bw,
                const float* __restrict__ bias, const int* __restrict__ mask,
                void* __restrict__ Cv, float* __restrict__ csum)
{
    __shared__ __align__(16) unsigned short As[128 * 128];  // 32 KB
    __shared__ __align__(16) unsigned short Bs[64 * 128];   // 16 KB

    const int tid  = threadIdx.x;
    const int lane = tid & 63;
    const int wv   = tid >> 6;      // wave 0..3
    const int wr   = wv >> 1;       // wave row (0..1) -> M
    const int wc   = wv & 1;        // wave col (0..1) -> N
    // XCD-aware swizzle (grid (16, 32)).
    const int id   = blockIdx.y * 16 + blockIdx.x;
    const int xcd  = id & 7;
    const int slot = id >> 3;
    const int by   = xcd * 4 + (slot >> 4);
    const int bx   = slot & 15;
    const int bm   = by * 128;
    const int bn   = bx * 64;
    const int m16  = lane & 15;
    const int kq   = lane >> 4;     // k-quarter (staging) / row-quad (C/D)

    f32x4 acc[4][2] = {};

    // Staging sources: wave wv stages A row-groups {2wv,2wv+1} x 4 k-chunks,
    // B row-group {wv} x 4 k-chunks (each chunk = 16 rows x 32 k = 1024 B).
    const int rg0 = 2 * wv, rg1 = 2 * wv + 1;
    const unsigned short* gA0 = A  + (size_t)(bm + 16 * rg0 + m16) * En + kq * 8;
    const unsigned short* gA1 = A  + (size_t)(bm + 16 * rg1 + m16) * En + kq * 8;
    const unsigned short* gB0 = Bw + (size_t)(bn + 16 * wv  + m16) * En + kq * 8;
    uint4* lA0 = (uint4*)&As[(rg0 * 4 + 0) * 512 + lane * 8];
    uint4* lA1 = (uint4*)&As[(rg0 * 4 + 1) * 512 + lane * 8];
    uint4* lA2 = (uint4*)&As[(rg0 * 4 + 2) * 512 + lane * 8];
    uint4* lA3 = (uint4*)&As[(rg0 * 4 + 3) * 512 + lane * 8];
    uint4* lA4 = (uint4*)&As[(rg1 * 4 + 0) * 512 + lane * 8];
    uint4* lA5 = (uint4*)&As[(rg1 * 4 + 1) * 512 + lane * 8];
    uint4* lA6 = (uint4*)&As[(rg1 * 4 + 2) * 512 + lane * 8];
    uint4* lA7 = (uint4*)&As[(rg1 * 4 + 3) * 512 + lane * 8];
    uint4* lB0 = (uint4*)&Bs[(wv * 4 + 0) * 512 + lane * 8];
    uint4* lB1 = (uint4*)&Bs[(wv * 4 + 1) * 512 + lane * 8];
    uint4* lB2 = (uint4*)&Bs[(wv * 4 + 2) * 512 + lane * 8];
    uint4* lB3 = (uint4*)&Bs[(wv * 4 + 3) * 512 + lane * 8];

    // 24 individually named staging registers — two 12-reg sets.
    uint4 pa0, pa1, pa2, pa3, pa4, pa5, pa6, pa7, pb0, pb1, pb2, pb3;
    uint4 qa0, qa1, qa2, qa3, qa4, qa5, qa6, qa7, qb0, qb1, qb2, qb3;

    LOAD12(p, 0);
    // K=1024, BK=128 -> 8 iterations, 2x unrolled (alternating reg sets).
#pragma unroll 1
    for (int it = 0; it < 4; ++it) {
        const int kbase = it * 256;
        __syncthreads();                 // prev compute's LDS reads done
        STORE12(p);                      // vmcnt waits for p (1 BK-128 phase old)
        __syncthreads();                 // writes visible
        LOAD12(q, kbase + 128);          // 12 loads in flight across the MFMAs
        COMPUTE128();

        __syncthreads();
        STORE12(q);
        __syncthreads();
        if (it < 3) { LOAD12(p, kbase + 256); }
        COMPUTE128();
    }

    // Epilogue. C/D layout: col = lane&15, row = (lane>>4)*4 + reg.
    float colsum[2] = {0.0f, 0.0f};
#pragma unroll
    for (int i = 0; i < 4; ++i) {
        const int r0 = bm + wr * 64 + i * 16 + kq * 4;
#pragma unroll
        for (int j = 0; j < 2; ++j) {
            const int c0 = bn + wc * 32 + j * 16 + m16;
            const float bcol = bias[c0];
#pragma unroll
            for (int r = 0; r < 4; ++r) {
                const int row = r0 + r;
                float val = acc[i][j][r] + bcol;
                if (APPLY_MASK) val = (mask[row] == 0) ? 0.0f : val;
                if (FUSE_CSUM) colsum[j] += val;
                if (OUT_BF16)
                    ((unsigned short*)Cv)[(size_t)row * En + c0] = f2bf(val);
                else
                    ((float*)Cv)[(size_t)row * En + c0] = val;
            }
        }
    }

    if (FUSE_CSUM) {
        // Wave wr's 64 rows are exactly global chunk gc = 2*by + wr.
        const int gc = 2 * by + wr;
#pragma unroll
        for (int j = 0; j < 2; ++j) {
            float s = colsum[j];
            s += __shfl_xor(s, 16, 64);
            s += __shfl_xor(s, 32, 64);
            if (kq == 0)
                csum[(size_t)gc * En + bn + wc * 32 + j * 16 + m16] = s;
        }
    }
}

// ---------------------------------------------------------------------------
// combine: inline exclusive scan of csum (32 chunk sums per column) +
// within-chunk prefix + weighted combine -> opre (bf16).
// out_pre[b,i,e] = (w2*Pref[i&~1] + (i odd)*w1*vm[i-1] + w0*(T - Pref[i])) / Z
// Z = (i&~1)*w2 + (i odd)*w1 + (S-i)*w0 + 1e-8   (pre-mask normalization)
// ---------------------------------------------------------------------------
__global__ __launch_bounds__(256)
void combine(const unsigned short* __restrict__ vm, const float* __restrict__ csum,
             const float* __restrict__ hier, unsigned short* __restrict__ opre)
{
    const int e = blockIdx.x * 256 + threadIdx.x;
    const int c = blockIdx.y;     // chunk within batch, 0..31
    const int b = blockIdx.z;
    const int h = e >> 6;   // dh = 64

    const float w0 = hier[((size_t)b * Hn + h) * 3 + 0];
    const float w1 = hier[((size_t)b * Hn + h) * 3 + 1] * 0.5f;
    const float w2 = hier[((size_t)b * Hn + h) * 3 + 2] * 0.25f;

    // Inline exclusive scan over this batch's 32 chunk sums (L2-hot).
    float run = 0.0f, T = 0.0f;
    const int g0 = b * NCH;
    for (int c2 = 0; c2 < NCH; ++c2) {
        const float v = csum[(size_t)(g0 + c2) * En + e];
        if (c2 < c) run += v;
        T += v;
    }

    float prev = 0.0f;
    const size_t base = ((size_t)b * Sn + c * CHUNK) * En + e;

    for (int t = 0; t < CHUNK; ++t) {
        const int i = c * CHUNK + t;
        const float cur = bf2f(vm[base + (size_t)t * En]);
        float num, Z;
        if (i & 1) {
            num = w2 * (run - prev) + w1 * prev + w0 * (T - run);
            Z = (float)(i - 1) * w2 + w1 + (float)(Sn - i) * w0 + 1e-8f;
        } else {
            num = w2 * run + w0 * (T - run);
            Z = (float)i * w2 + (float)(Sn - i) * w0 + 1e-8f;
        }
        opre[base + (size_t)t * En] = f2bf(num / Z);
        run += cur;
        prev = cur;
    }
}

// ---------------------------------------------------------------------------
extern "C" void kernel_launch(void* const* d_in, const int* in_sizes, int n_in,
                              void* d_out, int out_size, void* d_ws, size_t ws_size,
                              hipStream_t stream)
{
    // 0:x 1:attention_mask 2:level_indices 3:Wq 4:bq 5:Wk 6:bk 7:Wv 8:bv 9:hier 10:Wo 11:bo
    const float* x    = (const float*)d_in[0];
    const int*   mask = (const int*)d_in[1];
    const float* Wv   = (const float*)d_in[7];
    const float* bv   = (const float*)d_in[8];
    const float* hier = (const float*)d_in[9];
    const float* Wo   = (const float*)d_in[10];
    const float* bo   = (const float*)d_in[11];
    float* out = (float*)d_out;

    char* ws = (char*)d_ws;
    unsigned short* xb    = (unsigned short*)ws;  ws += (size_t)Mtot * En * 2;   // 8 MB
    unsigned short* Wvb   = (unsigned short*)ws;  ws += (size_t)En * En * 2;     // 2 MB
    unsigned short* Wob   = (unsigned short*)ws;  ws += (size_t)En * En * 2;     // 2 MB
    unsigned short* vmb   = (unsigned short*)ws;  ws += (size_t)Mtot * En * 2;   // 8 MB
    float*          csum  = (float*)ws;           ws += (size_t)GCH * En * 4;    // 256 KB
    unsigned short* opreb = (unsigned short*)ws;  ws += (size_t)Mtot * En * 2;   // 8 MB

    dim3 threads(256);

    // Fused casts to bf16 (x, Wv, Wo)
    cast3<<<dim3((XN + 2 * WN) / 1024), threads, 0, stream>>>(x, Wv, Wo, xb, Wvb, Wob);

    dim3 gemm_grid(16, 32);   // 512 blocks = 2/CU (XCD-swizzled in-kernel)

    // 1) vm = mask ? (x @ Wv.T + bv) : 0 (bf16) + fused per-chunk column sums
    gemm_bk128<true, true, true><<<gemm_grid, threads, 0, stream>>>(xb, Wvb, bv, mask, vmb, csum);
    // 2) weighted combine (inline csum scan) -> opre (bf16)
    combine<<<dim3(En / 256, NCH, Bn), threads, 0, stream>>>(vmb, csum, hier, opreb);
    // 3) out = opre @ Wo.T + bo (fp32 out)
    gemm_bk128<false, false, false><<<gemm_grid, threads, 0, stream>>>(opreb, Wob, bo, nullptr, out, nullptr);
}

// Round 13
// 166.628 us; speedup vs baseline: 1.1703x; 1.0287x over previous
//
#include <hip/hip_runtime.h>
#include <cstdint>
#include <cstddef>

// Problem constants (B, S, E, H, MAXLEN) = (2, 2048, 1024, 16, 2048)
constexpr int Sn = 2048;
constexpr int En = 1024;
constexpr int Bn = 2;
constexpr int Hn = 16;
constexpr int CHUNK = 32;          // R13: 32-row chunks (2 per wave tile)
constexpr int NCH = Sn / CHUNK;    // 64 chunks per batch
constexpr int Mtot = Bn * Sn;      // 4096
constexpr int GCH = Mtot / CHUNK;  // 128 global chunks

typedef __bf16 bf16x8 __attribute__((ext_vector_type(8)));
typedef float  f32x4  __attribute__((ext_vector_type(4)));

__device__ __forceinline__ unsigned short f2bf(float f) {
    union { float f; uint32_t u; } v; v.f = f;
    const uint32_t u = v.u;
    return (unsigned short)((u + 0x7fffu + ((u >> 16) & 1u)) >> 16);  // RNE
}
__device__ __forceinline__ float bf2f(unsigned short s) {
    union { uint32_t u; float f; } v; v.u = (uint32_t)s << 16; return v.f;
}

// ---------------------------------------------------------------------------
// Fused fp32 -> bf16 cast of x (XN), Wv (WN), Wo (WN) in one launch.
// ---------------------------------------------------------------------------
constexpr int XN = Bn * Sn * En;   // 4194304
constexpr int WN = En * En;        // 1048576

__global__ __launch_bounds__(256)
void cast3(const float* __restrict__ x, const float* __restrict__ Wv,
           const float* __restrict__ Wo, unsigned short* __restrict__ xb,
           unsigned short* __restrict__ Wvb, unsigned short* __restrict__ Wob)
{
    const int i = (blockIdx.x * 256 + threadIdx.x) * 4;
    const float* src; unsigned short* dst; int off;
    if (i < XN)           { src = x;  dst = xb;  off = i; }
    else if (i < XN + WN) { src = Wv; dst = Wvb; off = i - XN; }
    else                  { src = Wo; dst = Wob; off = i - XN - WN; }
    const float4 v = *(const float4*)(src + off);
    ushort4 o;
    o.x = f2bf(v.x); o.y = f2bf(v.y); o.z = f2bf(v.z); o.w = f2bf(v.w);
    *(ushort4*)(dst + off) = o;
}

// ---------------------------------------------------------------------------
// bf16 MFMA GEMM (NT) — R8's best-measured config, unchanged K-loop.
// C[m,n] = sum_k A[m,k]*W[n,k] + bias[n].
// Tile 128(M) x 64(N), BK=64, 256 threads = 4 waves in 2x2, wave tile 64x32.
// Staging: global -> 12 named uint4 VGPRs -> ds_write_b128 (loads for iter
// i+1 issue before iter i's compute; private VGPRs aren't drained at
// __syncthreads). LDS: 1024 B chunk = 16 rows x 32 k in fragment order,
// lane l -> slot l*16 B (conflict-free b128). XCD swizzle: xcd = id&7 owns
// 4 contiguous row-blocks (A 1 MB + B 2 MB < 4 MB per-XCD L2).
// R13 delta: FUSE_CSUM emits per-32-row chunk column sums — wave wr's 64
// rows = global chunks {4*by+2*wr, +1}; 16-row groups {0,1} -> first chunk,
// {2,3} -> second. Butterfly shuffle over kq, unique writer (kq==0).
// [Session note: six K-loop structures (BK 32/64/128, glds vs reg-prefetch,
// flatmm, 4-block occupancy) all land at ~40 µs/GEMM — empirical floor.]
// ---------------------------------------------------------------------------
#define LOAD6(k0, r0, r1, r2, r3, r4, r5)            \
    r0 = *(const uint4*)(gA0 + (k0));                \
    r1 = *(const uint4*)(gA0 + (k0) + 32);           \
    r2 = *(const uint4*)(gA1 + (k0));                \
    r3 = *(const uint4*)(gA1 + (k0) + 32);           \
    r4 = *(const uint4*)(gB0 + (k0));                \
    r5 = *(const uint4*)(gB0 + (k0) + 32);

#define STORE6(r0, r1, r2, r3, r4, r5)               \
    *lA00 = r0; *lA01 = r1;                          \
    *lA10 = r2; *lA11 = r3;                          \
    *lB00 = r4; *lB01 = r5;

#define COMPUTE()                                                                              \
    {                                                                                          \
        bf16x8 af[4][2], bfr[2][2];                                                            \
        _Pragma("unroll")                                                                      \
        for (int i = 0; i < 4; ++i)                                                            \
            _Pragma("unroll")                                                                  \
            for (int kh = 0; kh < 2; ++kh)                                                     \
                af[i][kh] = *(const bf16x8*)&As[((wr * 4 + i) * 2 + kh) * 512 + lane * 8];      \
        _Pragma("unroll")                                                                      \
        for (int j = 0; j < 2; ++j)                                                            \
            _Pragma("unroll")                                                                  \
            for (int kh = 0; kh < 2; ++kh)                                                     \
                bfr[j][kh] = *(const bf16x8*)&Bs[((wc * 2 + j) * 2 + kh) * 512 + lane * 8];     \
        _Pragma("unroll")                                                                      \
        for (int kh = 0; kh < 2; ++kh)                                                         \
            _Pragma("unroll")                                                                  \
            for (int i = 0; i < 4; ++i)                                                        \
                _Pragma("unroll")                                                              \
                for (int j = 0; j < 2; ++j)                                                    \
                    acc[i][j] = __builtin_amdgcn_mfma_f32_16x16x32_bf16(af[i][kh], bfr[j][kh], \
                                                                        acc[i][j], 0, 0, 0);   \
    }

template<bool APPLY_MASK, bool OUT_BF16, bool FUSE_CSUM>
__global__ __launch_bounds__(256)
void gemm_pipe(const unsigned short* __restrict__ A, const unsigned short* __restrict__ Bw,
               const float* __restrict__ bias, const int* __restrict__ mask,
               void* __restrict__ Cv, float* __restrict__ csum)
{
    __shared__ __align__(16) unsigned short As[128 * 64];  // 16 KB
    __shared__ __align__(16) unsigned short Bs[64 * 64];   // 8 KB

    const int tid  = threadIdx.x;
    const int lane = tid & 63;
    const int wv   = tid >> 6;      // wave 0..3
    const int wr   = wv >> 1;       // wave row (0..1) -> M
    const int wc   = wv & 1;        // wave col (0..1) -> N
    // XCD-aware swizzle (grid (16, 32)).
    const int id   = blockIdx.y * 16 + blockIdx.x;
    const int xcd  = id & 7;
    const int slot = id >> 3;
    const int by   = xcd * 4 + (slot >> 4);
    const int bx   = slot & 15;
    const int bm   = by * 128;
    const int bn   = bx * 64;
    const int m16  = lane & 15;
    const int kq   = lane >> 4;     // k-quarter (staging) / row-quad (C/D)

    f32x4 acc[4][2] = {};

    const int rg0 = 2 * wv, rg1 = 2 * wv + 1;
    const unsigned short* gA0 = A  + (size_t)(bm + 16 * rg0 + m16) * En + kq * 8;
    const unsigned short* gA1 = A  + (size_t)(bm + 16 * rg1 + m16) * En + kq * 8;
    const unsigned short* gB0 = Bw + (size_t)(bn + 16 * wv  + m16) * En + kq * 8;
    uint4* lA00 = (uint4*)&As[(rg0 * 2 + 0) * 512 + lane * 8];
    uint4* lA01 = (uint4*)&As[(rg0 * 2 + 1) * 512 + lane * 8];
    uint4* lA10 = (uint4*)&As[(rg1 * 2 + 0) * 512 + lane * 8];
    uint4* lA11 = (uint4*)&As[(rg1 * 2 + 1) * 512 + lane * 8];
    uint4* lB00 = (uint4*)&Bs[(wv  * 2 + 0) * 512 + lane * 8];
    uint4* lB01 = (uint4*)&Bs[(wv  * 2 + 1) * 512 + lane * 8];

    // 12 individually named staging registers (arrays spill — R6 lesson).
    uint4 p0, p1, p2, p3, p4, p5;
    uint4 q0, q1, q2, q3, q4, q5;

    LOAD6(0, p0, p1, p2, p3, p4, p5);
    // K=1024, BK=64 -> 16 iterations, 2x unrolled (alternating reg sets).
#pragma unroll 1
    for (int it = 0; it < 8; ++it) {
        const int kbase = it * 128;
        __syncthreads();                        // prev compute's LDS reads done
        STORE6(p0, p1, p2, p3, p4, p5);         // waits vmcnt for p (1 iter old)
        __syncthreads();                        // writes visible
        LOAD6(kbase + 64, q0, q1, q2, q3, q4, q5);   // in flight across MFMAs
        COMPUTE();

        __syncthreads();
        STORE6(q0, q1, q2, q3, q4, q5);
        __syncthreads();
        if (it < 7) { LOAD6(kbase + 128, p0, p1, p2, p3, p4, p5); }
        COMPUTE();
    }

    // Epilogue. C/D layout: col = lane&15, row = (lane>>4)*4 + reg.
    // colsum[g][j]: g = 32-row half of the wave tile (16-row groups {0,1} /
    // {2,3}), j = 16-col group.
    float colsum[2][2] = {{0.0f, 0.0f}, {0.0f, 0.0f}};
#pragma unroll
    for (int i = 0; i < 4; ++i) {
        const int r0 = bm + wr * 64 + i * 16 + kq * 4;
#pragma unroll
        for (int j = 0; j < 2; ++j) {
            const int c0 = bn + wc * 32 + j * 16 + m16;
            const float bcol = bias[c0];
#pragma unroll
            for (int r = 0; r < 4; ++r) {
                const int row = r0 + r;
                float val = acc[i][j][r] + bcol;
                if (APPLY_MASK) val = (mask[row] == 0) ? 0.0f : val;
                if (FUSE_CSUM) colsum[i >> 1][j] += val;
                if (OUT_BF16)
                    ((unsigned short*)Cv)[(size_t)row * En + c0] = f2bf(val);
                else
                    ((float*)Cv)[(size_t)row * En + c0] = val;
            }
        }
    }

    if (FUSE_CSUM) {
        // Wave wr's 64 rows = global chunks {4*by + 2*wr, +1} (CHUNK=32).
        const int gc0 = 4 * by + 2 * wr;
#pragma unroll
        for (int g = 0; g < 2; ++g)
#pragma unroll
            for (int j = 0; j < 2; ++j) {
                float s = colsum[g][j];
                s += __shfl_xor(s, 16, 64);
                s += __shfl_xor(s, 32, 64);
                if (kq == 0)
                    csum[(size_t)(gc0 + g) * En + bn + wc * 32 + j * 16 + m16] = s;
            }
    }
}

// ---------------------------------------------------------------------------
// combine: inline exclusive scan of csum (64 chunk sums per column) +
// within-chunk prefix + weighted combine -> opre (bf16).
// out_pre[b,i,e] = (w2*Pref[i&~1] + (i odd)*w1*vm[i-1] + w0*(T - Pref[i])) / Z
// Z = (i&~1)*w2 + (i odd)*w1 + (S-i)*w0 + 1e-8   (pre-mask normalization)
// R13: CHUNK=32 -> grid (4, 64, 2) = 512 blocks = 2/CU (2x R12's combine
// parallelism), serial depth 32. Chunk starts even, so odd-i prev is local.
// ---------------------------------------------------------------------------
__global__ __launch_bounds__(256)
void combine(const unsigned short* __restrict__ vm, const float* __restrict__ csum,
             const float* __restrict__ hier, unsigned short* __restrict__ opre)
{
    const int e = blockIdx.x * 256 + threadIdx.x;
    const int c = blockIdx.y;     // chunk within batch, 0..63
    const int b = blockIdx.z;
    const int h = e >> 6;   // dh = 64

    const float w0 = hier[((size_t)b * Hn + h) * 3 + 0];
    const float w1 = hier[((size_t)b * Hn + h) * 3 + 1] * 0.5f;
    const float w2 = hier[((size_t)b * Hn + h) * 3 + 2] * 0.25f;

    // Inline exclusive scan over this batch's 64 chunk sums (L2-hot, 512 KB).
    float run = 0.0f, T = 0.0f;
    const int g0 = b * NCH;
    for (int c2 = 0; c2 < NCH; ++c2) {
        const float v = csum[(size_t)(g0 + c2) * En + e];
        if (c2 < c) run += v;
        T += v;
    }

    float prev = 0.0f;
    const size_t base = ((size_t)b * Sn + c * CHUNK) * En + e;

    for (int t = 0; t < CHUNK; ++t) {
        const int i = c * CHUNK + t;
        const float cur = bf2f(vm[base + (size_t)t * En]);
        float num, Z;
        if (i & 1) {
            num = w2 * (run - prev) + w1 * prev + w0 * (T - run);
            Z = (float)(i - 1) * w2 + w1 + (float)(Sn - i) * w0 + 1e-8f;
        } else {
            num = w2 * run + w0 * (T - run);
            Z = (float)i * w2 + (float)(Sn - i) * w0 + 1e-8f;
        }
        opre[base + (size_t)t * En] = f2bf(num / Z);
        run += cur;
        prev = cur;
    }
}

// ---------------------------------------------------------------------------
extern "C" void kernel_launch(void* const* d_in, const int* in_sizes, int n_in,
                              void* d_out, int out_size, void* d_ws, size_t ws_size,
                              hipStream_t stream)
{
    // 0:x 1:attention_mask 2:level_indices 3:Wq 4:bq 5:Wk 6:bk 7:Wv 8:bv 9:hier 10:Wo 11:bo
    const float* x    = (const float*)d_in[0];
    const int*   mask = (const int*)d_in[1];
    const float* Wv   = (const float*)d_in[7];
    const float* bv   = (const float*)d_in[8];
    const float* hier = (const float*)d_in[9];
    const float* Wo   = (const float*)d_in[10];
    const float* bo   = (const float*)d_in[11];
    float* out = (float*)d_out;

    char* ws = (char*)d_ws;
    unsigned short* xb    = (unsigned short*)ws;  ws += (size_t)Mtot * En * 2;   // 8 MB
    unsigned short* Wvb   = (unsigned short*)ws;  ws += (size_t)En * En * 2;     // 2 MB
    unsigned short* Wob   = (unsigned short*)ws;  ws += (size_t)En * En * 2;     // 2 MB
    unsigned short* vmb   = (unsigned short*)ws;  ws += (size_t)Mtot * En * 2;   // 8 MB
    float*          csum  = (float*)ws;           ws += (size_t)GCH * En * 4;    // 512 KB
    unsigned short* opreb = (unsigned short*)ws;  ws += (size_t)Mtot * En * 2;   // 8 MB

    dim3 threads(256);

    // Fused casts to bf16 (x, Wv, Wo)
    cast3<<<dim3((XN + 2 * WN) / 1024), threads, 0, stream>>>(x, Wv, Wo, xb, Wvb, Wob);

    dim3 gemm_grid(16, 32);   // 512 blocks = 2/CU (XCD-swizzled in-kernel)

    // 1) vm = mask ? (x @ Wv.T + bv) : 0 (bf16) + fused 32-row chunk col sums
    gemm_pipe<true, true, true><<<gemm_grid, threads, 0, stream>>>(xb, Wvb, bv, mask, vmb, csum);
    // 2) weighted combine (inline csum scan) -> opre (bf16)
    combine<<<dim3(En / 256, NCH, Bn), threads, 0, stream>>>(vmb, csum, hier, opreb);
    // 3) out = opre @ Wo.T + bo (fp32 out)
    gemm_pipe<false, false, false><<<gemm_grid, threads, 0, stream>>>(opreb, Wob, bo, nullptr, out, nullptr);
}

// Round 14
// 165.994 us; speedup vs baseline: 1.1748x; 1.0038x over previous
//
#include <hip/hip_runtime.h>
#include <cstdint>
#include <cstddef>

// Problem constants (B, S, E, H, MAXLEN) = (2, 2048, 1024, 16, 2048)
constexpr int Sn = 2048;
constexpr int En = 1024;
constexpr int Bn = 2;
constexpr int Hn = 16;
constexpr int CHUNK = 32;          // 32-row chunks (2 per wave tile)
constexpr int NCH = Sn / CHUNK;    // 64 chunks per batch
constexpr int Mtot = Bn * Sn;      // 4096
constexpr int GCH = Mtot / CHUNK;  // 128 global chunks

typedef __bf16 bf16x8 __attribute__((ext_vector_type(8)));
typedef float  f32x4  __attribute__((ext_vector_type(4)));

__device__ __forceinline__ unsigned short f2bf(float f) {
    union { float f; uint32_t u; } v; v.f = f;
    const uint32_t u = v.u;
    return (unsigned short)((u + 0x7fffu + ((u >> 16) & 1u)) >> 16);  // RNE
}
__device__ __forceinline__ float bf2f(unsigned short s) {
    union { uint32_t u; float f; } v; v.u = (uint32_t)s << 16; return v.f;
}

// ---------------------------------------------------------------------------
// Fused fp32 -> bf16 cast of x (XN) and Wv (WN) in one launch.
// (Wo's cast lives in `combine` — it's only needed by gemm2, which runs
// after combine; this keeps cast3 off gemm2's inputs and 1/3 smaller.)
// ---------------------------------------------------------------------------
constexpr int XN = Bn * Sn * En;   // 4194304
constexpr int WN = En * En;        // 1048576

__global__ __launch_bounds__(256)
void cast2(const float* __restrict__ x, const float* __restrict__ Wv,
           unsigned short* __restrict__ xb, unsigned short* __restrict__ Wvb)
{
    const int i = (blockIdx.x * 256 + threadIdx.x) * 4;
    const float* src; unsigned short* dst; int off;
    if (i < XN) { src = x;  dst = xb;  off = i; }
    else        { src = Wv; dst = Wvb; off = i - XN; }
    const float4 v = *(const float4*)(src + off);
    ushort4 o;
    o.x = f2bf(v.x); o.y = f2bf(v.y); o.z = f2bf(v.z); o.w = f2bf(v.w);
    *(ushort4*)(dst + off) = o;
}

// ---------------------------------------------------------------------------
// bf16 MFMA GEMM (NT) — best-measured config (R8/R13), K-loop unchanged.
// C[m,n] = sum_k A[m,k]*W[n,k] + bias[n].
// Tile 128(M) x 64(N), BK=64, 256 threads = 4 waves in 2x2, wave tile 64x32.
// Staging: global -> 12 named uint4 VGPRs -> ds_write_b128 (loads for iter
// i+1 issue before iter i's compute; private VGPRs aren't drained at
// __syncthreads). LDS: 1024 B chunk = 16 rows x 32 k in fragment order,
// lane l -> slot l*16 B (conflict-free b128). XCD swizzle: xcd = id&7 owns
// 4 contiguous row-blocks (A 1 MB + B 2 MB < 4 MB per-XCD L2).
// FUSE_CSUM: per-32-row chunk column sums — wave wr's 64 rows = global
// chunks {4*by+2*wr, +1}; butterfly shuffle over kq, unique writer (kq==0).
// [Session: six K-loop structures (BK 32/64/128, glds vs reg-prefetch,
// flatmm, 4-blk occupancy) all ~40 µs/GEMM at this shape — consistent with
// m102's shape curve (N=1024 -> 90-320 TF for this family). Plateau.]
// ---------------------------------------------------------------------------
#define LOAD6(k0, r0, r1, r2, r3, r4, r5)            \
    r0 = *(const uint4*)(gA0 + (k0));                \
    r1 = *(const uint4*)(gA0 + (k0) + 32);           \
    r2 = *(const uint4*)(gA1 + (k0));                \
    r3 = *(const uint4*)(gA1 + (k0) + 32);           \
    r4 = *(const uint4*)(gB0 + (k0));                \
    r5 = *(const uint4*)(gB0 + (k0) + 32);

#define STORE6(r0, r1, r2, r3, r4, r5)               \
    *lA00 = r0; *lA01 = r1;                          \
    *lA10 = r2; *lA11 = r3;                          \
    *lB00 = r4; *lB01 = r5;

#define COMPUTE()                                                                              \
    {                                                                                          \
        bf16x8 af[4][2], bfr[2][2];                                                            \
        _Pragma("unroll")                                                                      \
        for (int i = 0; i < 4; ++i)                                                            \
            _Pragma("unroll")                                                                  \
            for (int kh = 0; kh < 2; ++kh)                                                     \
                af[i][kh] = *(const bf16x8*)&As[((wr * 4 + i) * 2 + kh) * 512 + lane * 8];      \
        _Pragma("unroll")                                                                      \
        for (int j = 0; j < 2; ++j)                                                            \
            _Pragma("unroll")                                                                  \
            for (int kh = 0; kh < 2; ++kh)                                                     \
                bfr[j][kh] = *(const bf16x8*)&Bs[((wc * 2 + j) * 2 + kh) * 512 + lane * 8];     \
        _Pragma("unroll")                                                                      \
        for (int kh = 0; kh < 2; ++kh)                                                         \
            _Pragma("unroll")                                                                  \
            for (int i = 0; i < 4; ++i)                                                        \
                _Pragma("unroll")                                                              \
                for (int j = 0; j < 2; ++j)                                                    \
                    acc[i][j] = __builtin_amdgcn_mfma_f32_16x16x32_bf16(af[i][kh], bfr[j][kh], \
                                                                        acc[i][j], 0, 0, 0);   \
    }

template<bool APPLY_MASK, bool OUT_BF16, bool FUSE_CSUM>
__global__ __launch_bounds__(256)
void gemm_pipe(const unsigned short* __restrict__ A, const unsigned short* __restrict__ Bw,
               const float* __restrict__ bias, const int* __restrict__ mask,
               void* __restrict__ Cv, float* __restrict__ csum)
{
    __shared__ __align__(16) unsigned short As[128 * 64];  // 16 KB
    __shared__ __align__(16) unsigned short Bs[64 * 64];   // 8 KB

    const int tid  = threadIdx.x;
    const int lane = tid & 63;
    const int wv   = tid >> 6;      // wave 0..3
    const int wr   = wv >> 1;       // wave row (0..1) -> M
    const int wc   = wv & 1;        // wave col (0..1) -> N
    // XCD-aware swizzle (grid (16, 32)).
    const int id   = blockIdx.y * 16 + blockIdx.x;
    const int xcd  = id & 7;
    const int slot = id >> 3;
    const int by   = xcd * 4 + (slot >> 4);
    const int bx   = slot & 15;
    const int bm   = by * 128;
    const int bn   = bx * 64;
    const int m16  = lane & 15;
    const int kq   = lane >> 4;     // k-quarter (staging) / row-quad (C/D)

    f32x4 acc[4][2] = {};

    const int rg0 = 2 * wv, rg1 = 2 * wv + 1;
    const unsigned short* gA0 = A  + (size_t)(bm + 16 * rg0 + m16) * En + kq * 8;
    const unsigned short* gA1 = A  + (size_t)(bm + 16 * rg1 + m16) * En + kq * 8;
    const unsigned short* gB0 = Bw + (size_t)(bn + 16 * wv  + m16) * En + kq * 8;
    uint4* lA00 = (uint4*)&As[(rg0 * 2 + 0) * 512 + lane * 8];
    uint4* lA01 = (uint4*)&As[(rg0 * 2 + 1) * 512 + lane * 8];
    uint4* lA10 = (uint4*)&As[(rg1 * 2 + 0) * 512 + lane * 8];
    uint4* lA11 = (uint4*)&As[(rg1 * 2 + 1) * 512 + lane * 8];
    uint4* lB00 = (uint4*)&Bs[(wv  * 2 + 0) * 512 + lane * 8];
    uint4* lB01 = (uint4*)&Bs[(wv  * 2 + 1) * 512 + lane * 8];

    // 12 individually named staging registers (arrays spill — R6 lesson).
    uint4 p0, p1, p2, p3, p4, p5;
    uint4 q0, q1, q2, q3, q4, q5;

    LOAD6(0, p0, p1, p2, p3, p4, p5);
    // K=1024, BK=64 -> 16 iterations, 2x unrolled (alternating reg sets).
#pragma unroll 1
    for (int it = 0; it < 8; ++it) {
        const int kbase = it * 128;
        __syncthreads();                        // prev compute's LDS reads done
        STORE6(p0, p1, p2, p3, p4, p5);         // waits vmcnt for p (1 iter old)
        __syncthreads();                        // writes visible
        LOAD6(kbase + 64, q0, q1, q2, q3, q4, q5);   // in flight across MFMAs
        COMPUTE();

        __syncthreads();
        STORE6(q0, q1, q2, q3, q4, q5);
        __syncthreads();
        if (it < 7) { LOAD6(kbase + 128, p0, p1, p2, p3, p4, p5); }
        COMPUTE();
    }

    // Epilogue. C/D layout: col = lane&15, row = (lane>>4)*4 + reg.
    // colsum[g][j]: g = 32-row half of the wave tile, j = 16-col group.
    float colsum[2][2] = {{0.0f, 0.0f}, {0.0f, 0.0f}};
#pragma unroll
    for (int i = 0; i < 4; ++i) {
        const int r0 = bm + wr * 64 + i * 16 + kq * 4;
#pragma unroll
        for (int j = 0; j < 2; ++j) {
            const int c0 = bn + wc * 32 + j * 16 + m16;
            const float bcol = bias[c0];
#pragma unroll
            for (int r = 0; r < 4; ++r) {
                const int row = r0 + r;
                float val = acc[i][j][r] + bcol;
                if (APPLY_MASK) val = (mask[row] == 0) ? 0.0f : val;
                if (FUSE_CSUM) colsum[i >> 1][j] += val;
                if (OUT_BF16)
                    ((unsigned short*)Cv)[(size_t)row * En + c0] = f2bf(val);
                else
                    ((float*)Cv)[(size_t)row * En + c0] = val;
            }
        }
    }

    if (FUSE_CSUM) {
        // Wave wr's 64 rows = global chunks {4*by + 2*wr, +1} (CHUNK=32).
        const int gc0 = 4 * by + 2 * wr;
#pragma unroll
        for (int g = 0; g < 2; ++g)
#pragma unroll
            for (int j = 0; j < 2; ++j) {
                float s = colsum[g][j];
                s += __shfl_xor(s, 16, 64);
                s += __shfl_xor(s, 32, 64);
                if (kq == 0)
                    csum[(size_t)(gc0 + g) * En + bn + wc * 32 + j * 16 + m16] = s;
            }
    }
}

// ---------------------------------------------------------------------------
// combine: Wo fp32->bf16 cast (issued first, hides in the scan stalls) +
// inline exclusive scan of csum (64 chunk sums per column) + within-chunk
// prefix + weighted combine -> opre (bf16).
// out_pre[b,i,e] = (w2*Pref[i&~1] + (i odd)*w1*vm[i-1] + w0*(T - Pref[i])) / Z
// Z = (i&~1)*w2 + (i odd)*w1 + (S-i)*w0 + 1e-8   (pre-mask normalization)
// Grid (4, 64, 2) = 512 blocks = 2/CU, serial depth 32. Chunk starts even,
// so odd-i prev is always in-chunk. gemm2 (reads Wob) launches after us.
// ---------------------------------------------------------------------------
__global__ __launch_bounds__(256)
void combine(const unsigned short* __restrict__ vm, const float* __restrict__ csum,
             const float* __restrict__ hier, const float* __restrict__ Wo,
             unsigned short* __restrict__ Wob, unsigned short* __restrict__ opre)
{
    // --- Wo cast slice: 512 blocks x 256 threads x 8 elems = 1M elements.
    {
        const int fid = (blockIdx.z * 64 + blockIdx.y) * 4 + blockIdx.x;  // 0..511
        const int base = fid * 2048 + threadIdx.x * 4;                    // first half
#pragma unroll
        for (int half = 0; half < 2; ++half) {
            const int off = base + half * 1024;
            const float4 v = *(const float4*)(Wo + off);
            ushort4 o;
            o.x = f2bf(v.x); o.y = f2bf(v.y); o.z = f2bf(v.z); o.w = f2bf(v.w);
            *(ushort4*)(Wob + off) = o;
        }
    }

    const int e = blockIdx.x * 256 + threadIdx.x;
    const int c = blockIdx.y;     // chunk within batch, 0..63
    const int b = blockIdx.z;
    const int h = e >> 6;   // dh = 64

    const float w0 = hier[((size_t)b * Hn + h) * 3 + 0];
    const float w1 = hier[((size_t)b * Hn + h) * 3 + 1] * 0.5f;
    const float w2 = hier[((size_t)b * Hn + h) * 3 + 2] * 0.25f;

    // Inline exclusive scan over this batch's 64 chunk sums (L2-hot, 512 KB).
    float run = 0.0f, T = 0.0f;
    const int g0 = b * NCH;
    for (int c2 = 0; c2 < NCH; ++c2) {
        const float v = csum[(size_t)(g0 + c2) * En + e];
        if (c2 < c) run += v;
        T += v;
    }

    float prev = 0.0f;
    const size_t base = ((size_t)b * Sn + c * CHUNK) * En + e;

    for (int t = 0; t < CHUNK; ++t) {
        const int i = c * CHUNK + t;
        const float cur = bf2f(vm[base + (size_t)t * En]);
        float num, Z;
        if (i & 1) {
            num = w2 * (run - prev) + w1 * prev + w0 * (T - run);
            Z = (float)(i - 1) * w2 + w1 + (float)(Sn - i) * w0 + 1e-8f;
        } else {
            num = w2 * run + w0 * (T - run);
            Z = (float)i * w2 + (float)(Sn - i) * w0 + 1e-8f;
        }
        opre[base + (size_t)t * En] = f2bf(num / Z);
        run += cur;
        prev = cur;
    }
}

// ---------------------------------------------------------------------------
extern "C" void kernel_launch(void* const* d_in, const int* in_sizes, int n_in,
                              void* d_out, int out_size, void* d_ws, size_t ws_size,
                              hipStream_t stream)
{
    // 0:x 1:attention_mask 2:level_indices 3:Wq 4:bq 5:Wk 6:bk 7:Wv 8:bv 9:hier 10:Wo 11:bo
    const float* x    = (const float*)d_in[0];
    const int*   mask = (const int*)d_in[1];
    const float* Wv   = (const float*)d_in[7];
    const float* bv   = (const float*)d_in[8];
    const float* hier = (const float*)d_in[9];
    const float* Wo   = (const float*)d_in[10];
    const float* bo   = (const float*)d_in[11];
    float* out = (float*)d_out;

    char* ws = (char*)d_ws;
    unsigned short* xb    = (unsigned short*)ws;  ws += (size_t)Mtot * En * 2;   // 8 MB
    unsigned short* Wvb   = (unsigned short*)ws;  ws += (size_t)En * En * 2;     // 2 MB
    unsigned short* Wob   = (unsigned short*)ws;  ws += (size_t)En * En * 2;     // 2 MB
    unsigned short* vmb   = (unsigned short*)ws;  ws += (size_t)Mtot * En * 2;   // 8 MB
    float*          csum  = (float*)ws;           ws += (size_t)GCH * En * 4;    // 512 KB
    unsigned short* opreb = (unsigned short*)ws;  ws += (size_t)Mtot * En * 2;   // 8 MB

    dim3 threads(256);

    // Casts to bf16: x + Wv only (Wo is cast inside combine, pre-gemm2)
    cast2<<<dim3((XN + WN) / 1024), threads, 0, stream>>>(x, Wv, xb, Wvb);

    dim3 gemm_grid(16, 32);   // 512 blocks = 2/CU (XCD-swizzled in-kernel)

    // 1) vm = mask ? (x @ Wv.T + bv) : 0 (bf16) + fused 32-row chunk col sums
    gemm_pipe<true, true, true><<<gemm_grid, threads, 0, stream>>>(xb, Wvb, bv, mask, vmb, csum);
    // 2) Wo cast + weighted combine (inline csum scan) -> opre (bf16)
    combine<<<dim3(En / 256, NCH, Bn), threads, 0, stream>>>(vmb, csum, hier, Wo, Wob, opreb);
    // 3) out = opre @ Wo.T + bo (fp32 out)
    gemm_pipe<false, false, false><<<gemm_grid, threads, 0, stream>>>(opreb, Wob, bo, nullptr, out, nullptr);
}